// Round 19
// baseline (25.141 us; speedup 1.0000x reference)
//
#include <hip/hip_runtime.h>
#include <hip/hip_bf16.h>

typedef __attribute__((ext_vector_type(4))) float f32x4;
typedef __attribute__((ext_vector_type(8))) short short8;

#define NB 8192
#define ND 256
#define NK 32
#define PADF 520  // AcT/AqT row stride (ushort): 1040B; bank stride 4 -> 2-way (free)

static __device__ __forceinline__ unsigned short f2bf(float f) {
  return __builtin_bit_cast(unsigned short, __float2bfloat16(f));
}

static __device__ __forceinline__ f32x4 mfma_bf16(short8 a, short8 b, f32x4 c) {
  return __builtin_amdgcn_mfma_f32_16x16x32_bf16(a, b, c, 0, 0, 0);
}

static __device__ __forceinline__ short8 pack_bf16x8(float4 lo, float4 hi) {
  short8 r;
  r[0] = (short)f2bf(lo.x); r[1] = (short)f2bf(lo.y);
  r[2] = (short)f2bf(lo.z); r[3] = (short)f2bf(lo.w);
  r[4] = (short)f2bf(hi.x); r[5] = (short)f2bf(hi.y);
  r[6] = (short)f2bf(hi.z); r[7] = (short)f2bf(hi.w);
  return r;
}

// ---- kernel 0: prep, vectorized 8x (unchanged from R17) --------------------
__global__ __launch_bounds__(256) void prep_k(const float* __restrict__ wmu,
                                              const float* __restrict__ wsig,
                                              __hip_bfloat16* __restrict__ wsw,
                                              const float* __restrict__ mu_c,
                                              const float* __restrict__ lsc,
                                              __hip_bfloat16* __restrict__ bcsw,
                                              float* __restrict__ c3k,
                                              float* __restrict__ ckk) {
  __shared__ float red1[4], red2[4];
  const int blk = blockIdx.x, tid = threadIdx.x;
  if (blk < 64) {
    int i0 = blk * 2048 + tid * 8;     // 64*2048 = 131072 = 512*256
    int f = i0 >> 9, r = i0 & 511;
    int l = r >> 3;                    // e = 0..7 within this thread
    int n = (f >> 3) * 16 + (l & 15);             // Wcat row
    int k0 = (f & 7) * 32 + ((l >> 4) << 3);      // Wcat col base
    const float* src = (n < 256) ? (wmu + n * ND + k0) : (wsig + (n - 256) * ND + k0);
    float4 v0 = *reinterpret_cast<const float4*>(src);
    float4 v1 = *reinterpret_cast<const float4*>(src + 4);
    *reinterpret_cast<short8*>(wsw + i0) = pack_bf16x8(v0, v1);
  } else {
    int k = blk - 64;     // cluster index
    int d = tid;
    float l = lsc[k * ND + d];
    float inv = __expf(-l);
    float mc = mu_c[k * ND + d];
    const int rb = k >> 4, lrow = k & 15;
    {
      int c = d;
      int kb = c >> 5, q = (c >> 3) & 3, e = c & 7;
      bcsw[(size_t)(rb * 16 + kb) * 512 + (q * 16 + lrow) * 8 + e] = __float2bfloat16(inv);
    }
    {
      int c = 256 + d;
      int kb = c >> 5, q = (c >> 3) & 3, e = c & 7;
      bcsw[(size_t)(rb * 16 + kb) * 512 + (q * 16 + lrow) * 8 + e] = __float2bfloat16(-2.f * mc * inv);
    }
    float s1 = l, s2 = mc * mc * inv;
    #pragma unroll
    for (int sh = 32; sh; sh >>= 1) { s1 += __shfl_xor(s1, sh); s2 += __shfl_xor(s2, sh); }
    int lane = tid & 63, wv = tid >> 6;
    if (lane == 0) { red1[wv] = s1; red2[wv] = s2; }
    __syncthreads();
    if (tid == 0) {
      float t1 = red1[0] + red1[1] + red1[2] + red1[3];
      float t2 = red2[0] + red2[1] + red2[2] + red2[3];
      c3k[k] = t2;
      ckk[k] = t1 + t2;
    }
  }
}

// ---- kernel 1: mega — R18 + hoisted round-0 sig W-frag loads ----------------
// 512 blocks x 512 thr (8 waves, 2 blocks/CU; wall time = block critical path).
// Pipelining state: round-0 mu (bM0) AND sig (bS0) W-frag batches issued
// BEFORE the x-staging barrier; phase-2 Bcsw frags issued before barrier #2.
__global__ __launch_bounds__(512, 4) void mega_k(const float* __restrict__ xf,
                                                 const __hip_bfloat16* __restrict__ wsw,
                                                 const float* __restrict__ bmu,
                                                 const float* __restrict__ bsigv,
                                                 const float* __restrict__ eps,
                                                 const __hip_bfloat16* __restrict__ bcsw,
                                                 const float* __restrict__ c3k,
                                                 const float* __restrict__ ckk,
                                                 float* __restrict__ zout,
                                                 float* __restrict__ part) {
  __shared__ __align__(16) unsigned short AcT[16][PADF];
  __shared__ __align__(16) unsigned short AqT[16][PADF];
  __shared__ __align__(16) char uniBuf[33792];   // Axb [16][264] ushort | sW [8][2][16][33] f32
  __shared__ float piP[NK];
  __shared__ float gSum;
  unsigned short (*Axb)[264] = (unsigned short (*)[264])uniBuf;
  float (*sW)[2][16][33] = (float (*)[2][16][33])uniBuf;

  const int tid = threadIdx.x, lane = tid & 63, w = tid >> 6;   // w in [0,8)
  const int lrow = lane & 15, q = lane >> 4;
  const int m0 = blockIdx.x * 16;

  if (tid < NK) piP[tid] = 0.f;
  if (tid == NK) gSum = 0.f;

  // ---- HOIST: round-0 mu AND sig W-frag loads (independent of LDS barrier)
  short8 bM0[8], bS0[8];
  {
    const __hip_bfloat16* pM0 = wsw + (size_t)(w * 8) * 512 + lane * 8;
    const __hip_bfloat16* pS0 = wsw + (size_t)((16 + w) * 8) * 512 + lane * 8;
    #pragma unroll
    for (int kk = 0; kk < 8; ++kk) {
      bM0[kk] = *reinterpret_cast<const short8*>(pM0 + kk * 512);
      bS0[kk] = *reinterpret_cast<const short8*>(pS0 + kk * 512);
    }
  }

  // ---- prefetch bias + eps for this wave's two rounds (rb = r*8 + w)
  float bmv[2], bsv[2], epv[2][4];
  #pragma unroll
  for (int r = 0; r < 2; ++r) {
    const int d = (r * 8 + w) * 16 + lrow;
    bmv[r] = bmu[d];
    bsv[r] = bsigv[d];
    #pragma unroll
    for (int j = 0; j < 4; ++j)
      epv[r][j] = eps[(size_t)(m0 + q * 4 + j) * ND + d];
  }

  // ---- stage x -> bf16 Axb: thread t covers row t>>5, 8 cols from (t&31)*8
  {
    const int r = tid >> 5, c0 = (tid & 31) * 8;
    const float* xr = xf + (size_t)(m0 + r) * ND + c0;
    float4 a0 = *reinterpret_cast<const float4*>(xr);
    float4 a1 = *reinterpret_cast<const float4*>(xr + 4);
    *reinterpret_cast<short8*>(&Axb[r][c0]) = pack_bf16x8(a0, a1);
  }
  __syncthreads();

  // ---- hoisted A fragments (whole K=256, held for both rounds)
  short8 aF[8];
  #pragma unroll
  for (int kk = 0; kk < 8; ++kk)
    aF[kk] = *reinterpret_cast<const short8*>(&Axb[lrow][kk * 32 + q * 8]);

  // ---- phase 1: 2 rounds of (frag loads + 16 MFMAs + epilogue)
  #pragma unroll
  for (int r = 0; r < 2; ++r) {
    const int rb = r * 8 + w;                 // mu row-block; sig = 16 + rb
    const __hip_bfloat16* pM = wsw + (size_t)(rb * 8) * 512 + lane * 8;
    const __hip_bfloat16* pS = wsw + (size_t)((16 + rb) * 8) * 512 + lane * 8;
    f32x4 aM = (f32x4){0.f, 0.f, 0.f, 0.f};
    f32x4 aS = (f32x4){0.f, 0.f, 0.f, 0.f};
    {
      short8 bM[8];
      #pragma unroll
      for (int kk = 0; kk < 8; ++kk)
        bM[kk] = (r == 0) ? bM0[kk]
                          : *reinterpret_cast<const short8*>(pM + kk * 512);
      #pragma unroll
      for (int kk = 0; kk < 8; ++kk)
        aM = mfma_bf16(aF[kk], bM[kk], aM);
    }
    {
      short8 bS[8];
      #pragma unroll
      for (int kk = 0; kk < 8; ++kk)
        bS[kk] = (r == 0) ? bS0[kk]
                          : *reinterpret_cast<const short8*>(pS + kk * 512);
      #pragma unroll
      for (int kk = 0; kk < 8; ++kk)
        aS = mfma_bf16(aF[kk], bS[kk], aS);
    }
    // per-round epilogue: C/D layout col(lrow)->d, row(q*4+j)->b
    const int d = rb * 16 + lrow;
    #pragma unroll
    for (int j = 0; j < 4; ++j) {
      const int bl = q * 4 + j;
      const int b = m0 + bl;
      float muv = aM[j] + bmv[r];
      float lsv = aS[j] + bsv[r];
      float sq  = __expf(lsv);
      float zv  = muv + sqrtf(sq) * epv[r][j];
      zout[(size_t)b * ND + d] = zv;
      AcT[bl][d]       = f2bf(zv * zv);
      AcT[bl][256 + d] = f2bf(zv);
      AqT[bl][d]       = f2bf(sq + muv * muv);
      AqT[bl][256 + d] = f2bf(muv);
    }
  }

  // ---- HOIST: phase-2 Bcsw frag loads before the barrier
  short8 b0v[2], b1v[2];
  #pragma unroll
  for (int ks = 0; ks < 2; ++ks) {
    const int kb = w * 2 + ks;              // 32-col block index (0..15)
    b0v[ks] = *reinterpret_cast<const short8*>(bcsw + (size_t)kb * 512 + lane * 8);
    b1v[ks] = *reinterpret_cast<const short8*>(bcsw + (size_t)(16 + kb) * 512 + lane * 8);
  }
  __syncthreads();   // AcT/AqT ready; Axb dead -> sW region usable

  // ---- phase 2: cluster GEMMs (64-feature slice per wave)
  f32x4 cL[2], cQ[2];
  cL[0] = cL[1] = cQ[0] = cQ[1] = (f32x4){0.f, 0.f, 0.f, 0.f};
  {
    short8 acv[2], aqv[2];
    #pragma unroll
    for (int ks = 0; ks < 2; ++ks) {
      const int kc = (w * 2 + ks) * 32 + q * 8;
      acv[ks] = *reinterpret_cast<const short8*>(&AcT[lrow][kc]);
      aqv[ks] = *reinterpret_cast<const short8*>(&AqT[lrow][kc]);
    }
    #pragma unroll
    for (int ks = 0; ks < 2; ++ks) {
      cL[0] = mfma_bf16(acv[ks], b0v[ks], cL[0]);
      cL[1] = mfma_bf16(acv[ks], b1v[ks], cL[1]);
      cQ[0] = mfma_bf16(aqv[ks], b0v[ks], cQ[0]);
      cQ[1] = mfma_bf16(aqv[ks], b1v[ks], cQ[1]);
    }
  }
  #pragma unroll
  for (int nfk = 0; nfk < 2; ++nfk)
    #pragma unroll
    for (int j = 0; j < 4; ++j) {
      sW[w][0][q * 4 + j][nfk * 16 + lrow] = cL[nfk][j];
      sW[w][1][q * 4 + j][nfk * 16 + lrow] = cQ[nfk][j];
    }
  __syncthreads();

  // ---- epilogue 2: softmax + loss partials (first 4 waves)
  if (tid < 256) {
    const int b = tid >> 4, kk = tid & 15;
    float L0 = 0.f, L1 = 0.f, Q0 = 0.f, Q1 = 0.f;
    #pragma unroll
    for (int ww = 0; ww < 8; ++ww) {
      L0 += sW[ww][0][b][kk];      L1 += sW[ww][0][b][kk + 16];
      Q0 += sW[ww][1][b][kk];      Q1 += sW[ww][1][b][kk + 16];
    }
    float l0 = -(L0 + c3k[kk]);
    float l1 = -(L1 + c3k[kk + 16]);
    float mx = fmaxf(l0, l1);
    #pragma unroll
    for (int s = 8; s; s >>= 1) mx = fmaxf(mx, __shfl_xor(mx, s));
    float p0 = __expf(l0 - mx), p1 = __expf(l1 - mx);
    float ps = p0 + p1;
    #pragma unroll
    for (int s = 8; s; s >>= 1) ps += __shfl_xor(ps, s);
    float pi0 = p0 / ps + 1e-10f;
    float pi1 = p1 / ps + 1e-10f;
    float g = pi0 * (Q0 + ckk[kk]) + pi1 * (Q1 + ckk[kk + 16]);
    #pragma unroll
    for (int s = 8; s; s >>= 1) g += __shfl_xor(g, s);
    atomicAdd(&piP[kk], pi0);
    atomicAdd(&piP[kk + 16], pi1);
    if (kk == 0) atomicAdd(&gSum, g);
  }
  __syncthreads();
  if (tid < NK)  part[(size_t)tid * 512 + blockIdx.x] = piP[tid];
  if (tid == NK) part[(size_t)NK * 512 + blockIdx.x] = 0.5f * gSum;
}

// ---- kernel 2: final reduce — parallelized (unchanged from R17) ------------
__global__ __launch_bounds__(320) void final_k(const float* __restrict__ part,
                                               float* __restrict__ out) {
  __shared__ float red[33][8];
  const int tid = threadIdx.x;
  if (tid < 264) {
    const int c = tid >> 3, sg = tid & 7;
    const float4* p4 = reinterpret_cast<const float4*>(part + (size_t)c * 512 + sg * 64);
    float s = 0.f;
    #pragma unroll
    for (int i = 0; i < 16; ++i) {
      float4 v = p4[i];
      s += v.x + v.y + v.z + v.w;
    }
    red[c][sg] = s;
  }
  __syncthreads();
  if (tid >= 64) return;
  float s = 0.f;
  if (tid < 33) {
    #pragma unroll
    for (int sg = 0; sg < 8; ++sg) s += red[tid][sg];
  }
  if (tid == 32) out[NB * ND] = s;                 // batch_gaussian_loss
  float t = 0.f;
  if (tid < 32) { float mk = s / (float)NB; t = mk * __logf(mk); }
  #pragma unroll
  for (int sh = 16; sh; sh >>= 1) t += __shfl_xor(t, sh);
  if (tid == 0) out[NB * ND + 1] = t / (float)NK;  // batch_uniform_loss
}

extern "C" void kernel_launch(void* const* d_in, const int* in_sizes, int n_in,
                              void* d_out, int out_size, void* d_ws, size_t ws_size,
                              hipStream_t stream) {
  const float* x    = (const float*)d_in[0];
  const float* eps  = (const float*)d_in[1];
  const float* wmu  = (const float*)d_in[2];
  const float* bmu  = (const float*)d_in[3];
  const float* wsig = (const float*)d_in[4];
  const float* bsig = (const float*)d_in[5];
  const float* mu_c = (const float*)d_in[6];
  const float* lsc  = (const float*)d_in[7];
  float* out = (float*)d_out;

  char* ws = (char*)d_ws;
  __hip_bfloat16* wsw  = (__hip_bfloat16*)ws;                      // 256 KiB
  __hip_bfloat16* bcsw = (__hip_bfloat16*)(ws + (256u << 10));     // 32 KiB
  float* c3k  = (float*)(ws + (288u << 10));                       // 128 B
  float* ckk  = (float*)(ws + (288u << 10) + 256u);                // 128 B
  float* part = (float*)(ws + (288u << 10) + 512u);                // 66 KiB

  prep_k<<<96, 256, 0, stream>>>(wmu, wsig, wsw, mu_c, lsc, bcsw, c3k, ckk);
  mega_k<<<512, 512, 0, stream>>>(x, wsw, bmu, bsig, eps, bcsw, c3k, ckk, out, part);
  final_k<<<1, 320, 0, stream>>>(part, out);
}

// Round 20
// 24.658 us; speedup vs baseline: 1.0196x; 1.0196x over previous
//
#include <hip/hip_runtime.h>
#include <hip/hip_bf16.h>

typedef __attribute__((ext_vector_type(4))) float f32x4;
typedef __attribute__((ext_vector_type(8))) short short8;

#define NB 8192
#define ND 256
#define NK 32
#define PADF 520  // AcT/AqT row stride (ushort): 1040B; bank stride 4 -> 2-way (free)

static __device__ __forceinline__ unsigned short f2bf(float f) {
  return __builtin_bit_cast(unsigned short, __float2bfloat16(f));
}

static __device__ __forceinline__ f32x4 mfma_bf16(short8 a, short8 b, f32x4 c) {
  return __builtin_amdgcn_mfma_f32_16x16x32_bf16(a, b, c, 0, 0, 0);
}

static __device__ __forceinline__ short8 pack_bf16x8(float4 lo, float4 hi) {
  short8 r;
  r[0] = (short)f2bf(lo.x); r[1] = (short)f2bf(lo.y);
  r[2] = (short)f2bf(lo.z); r[3] = (short)f2bf(lo.w);
  r[4] = (short)f2bf(hi.x); r[5] = (short)f2bf(hi.y);
  r[6] = (short)f2bf(hi.z); r[7] = (short)f2bf(hi.w);
  return r;
}

// ---- kernel 0: prep, vectorized 8x ------------------------------------------
__global__ __launch_bounds__(256) void prep_k(const float* __restrict__ wmu,
                                              const float* __restrict__ wsig,
                                              __hip_bfloat16* __restrict__ wsw,
                                              const float* __restrict__ mu_c,
                                              const float* __restrict__ lsc,
                                              __hip_bfloat16* __restrict__ bcsw,
                                              float* __restrict__ c3k,
                                              float* __restrict__ ckk) {
  __shared__ float red1[4], red2[4];
  const int blk = blockIdx.x, tid = threadIdx.x;
  if (blk < 64) {
    int i0 = blk * 2048 + tid * 8;     // 64*2048 = 131072 = 512*256
    int f = i0 >> 9, r = i0 & 511;
    int l = r >> 3;                    // e = 0..7 within this thread
    int n = (f >> 3) * 16 + (l & 15);             // Wcat row
    int k0 = (f & 7) * 32 + ((l >> 4) << 3);      // Wcat col base
    const float* src = (n < 256) ? (wmu + n * ND + k0) : (wsig + (n - 256) * ND + k0);
    float4 v0 = *reinterpret_cast<const float4*>(src);
    float4 v1 = *reinterpret_cast<const float4*>(src + 4);
    *reinterpret_cast<short8*>(wsw + i0) = pack_bf16x8(v0, v1);
  } else {
    int k = blk - 64;     // cluster index
    int d = tid;
    float l = lsc[k * ND + d];
    float inv = __expf(-l);
    float mc = mu_c[k * ND + d];
    const int rb = k >> 4, lrow = k & 15;
    {
      int c = d;
      int kb = c >> 5, q = (c >> 3) & 3, e = c & 7;
      bcsw[(size_t)(rb * 16 + kb) * 512 + (q * 16 + lrow) * 8 + e] = __float2bfloat16(inv);
    }
    {
      int c = 256 + d;
      int kb = c >> 5, q = (c >> 3) & 3, e = c & 7;
      bcsw[(size_t)(rb * 16 + kb) * 512 + (q * 16 + lrow) * 8 + e] = __float2bfloat16(-2.f * mc * inv);
    }
    float s1 = l, s2 = mc * mc * inv;
    #pragma unroll
    for (int sh = 32; sh; sh >>= 1) { s1 += __shfl_xor(s1, sh); s2 += __shfl_xor(s2, sh); }
    int lane = tid & 63, wv = tid >> 6;
    if (lane == 0) { red1[wv] = s1; red2[wv] = s2; }
    __syncthreads();
    if (tid == 0) {
      float t1 = red1[0] + red1[1] + red1[2] + red1[3];
      float t2 = red2[0] + red2[1] + red2[2] + red2[3];
      c3k[k] = t2;
      ckk[k] = t1 + t2;
    }
  }
}

// ---- kernel 1: mega — R18 champion (hoisted bM0 + Bcsw, NOT bS0) -----------
// 512 blocks x 512 thr (8 waves, 2 blocks/CU; wall time = block critical path).
// Pipelining: round-0 mu W-frags (bM0) issued before the x-staging barrier;
// phase-2 Bcsw frags issued before barrier #2. bS0 hoist regresses (VGPR cap).
__global__ __launch_bounds__(512, 4) void mega_k(const float* __restrict__ xf,
                                                 const __hip_bfloat16* __restrict__ wsw,
                                                 const float* __restrict__ bmu,
                                                 const float* __restrict__ bsigv,
                                                 const float* __restrict__ eps,
                                                 const __hip_bfloat16* __restrict__ bcsw,
                                                 const float* __restrict__ c3k,
                                                 const float* __restrict__ ckk,
                                                 float* __restrict__ zout,
                                                 float* __restrict__ part) {
  __shared__ __align__(16) unsigned short AcT[16][PADF];
  __shared__ __align__(16) unsigned short AqT[16][PADF];
  __shared__ __align__(16) char uniBuf[33792];   // Axb [16][264] ushort | sW [8][2][16][33] f32
  __shared__ float piP[NK];
  __shared__ float gSum;
  unsigned short (*Axb)[264] = (unsigned short (*)[264])uniBuf;
  float (*sW)[2][16][33] = (float (*)[2][16][33])uniBuf;

  const int tid = threadIdx.x, lane = tid & 63, w = tid >> 6;   // w in [0,8)
  const int lrow = lane & 15, q = lane >> 4;
  const int m0 = blockIdx.x * 16;

  if (tid < NK) piP[tid] = 0.f;
  if (tid == NK) gSum = 0.f;

  // ---- HOIST: round-0 mu W-frag loads (independent of LDS barrier)
  short8 bM0[8];
  {
    const __hip_bfloat16* pM0 = wsw + (size_t)(w * 8) * 512 + lane * 8;
    #pragma unroll
    for (int kk = 0; kk < 8; ++kk)
      bM0[kk] = *reinterpret_cast<const short8*>(pM0 + kk * 512);
  }

  // ---- prefetch bias + eps for this wave's two rounds (rb = r*8 + w)
  float bmv[2], bsv[2], epv[2][4];
  #pragma unroll
  for (int r = 0; r < 2; ++r) {
    const int d = (r * 8 + w) * 16 + lrow;
    bmv[r] = bmu[d];
    bsv[r] = bsigv[d];
    #pragma unroll
    for (int j = 0; j < 4; ++j)
      epv[r][j] = eps[(size_t)(m0 + q * 4 + j) * ND + d];
  }

  // ---- stage x -> bf16 Axb: thread t covers row t>>5, 8 cols from (t&31)*8
  {
    const int r = tid >> 5, c0 = (tid & 31) * 8;
    const float* xr = xf + (size_t)(m0 + r) * ND + c0;
    float4 a0 = *reinterpret_cast<const float4*>(xr);
    float4 a1 = *reinterpret_cast<const float4*>(xr + 4);
    *reinterpret_cast<short8*>(&Axb[r][c0]) = pack_bf16x8(a0, a1);
  }
  __syncthreads();

  // ---- hoisted A fragments (whole K=256, held for both rounds)
  short8 aF[8];
  #pragma unroll
  for (int kk = 0; kk < 8; ++kk)
    aF[kk] = *reinterpret_cast<const short8*>(&Axb[lrow][kk * 32 + q * 8]);

  // ---- phase 1: 2 rounds of (frag loads + 16 MFMAs + epilogue)
  #pragma unroll
  for (int r = 0; r < 2; ++r) {
    const int rb = r * 8 + w;                 // mu row-block; sig = 16 + rb
    const __hip_bfloat16* pM = wsw + (size_t)(rb * 8) * 512 + lane * 8;
    const __hip_bfloat16* pS = wsw + (size_t)((16 + rb) * 8) * 512 + lane * 8;
    f32x4 aM = (f32x4){0.f, 0.f, 0.f, 0.f};
    f32x4 aS = (f32x4){0.f, 0.f, 0.f, 0.f};
    {
      short8 bM[8];
      #pragma unroll
      for (int kk = 0; kk < 8; ++kk)
        bM[kk] = (r == 0) ? bM0[kk]
                          : *reinterpret_cast<const short8*>(pM + kk * 512);
      #pragma unroll
      for (int kk = 0; kk < 8; ++kk)
        aM = mfma_bf16(aF[kk], bM[kk], aM);
    }
    {
      short8 bS[8];
      #pragma unroll
      for (int kk = 0; kk < 8; ++kk)
        bS[kk] = *reinterpret_cast<const short8*>(pS + kk * 512);
      #pragma unroll
      for (int kk = 0; kk < 8; ++kk)
        aS = mfma_bf16(aF[kk], bS[kk], aS);
    }
    // per-round epilogue: C/D layout col(lrow)->d, row(q*4+j)->b
    const int d = rb * 16 + lrow;
    #pragma unroll
    for (int j = 0; j < 4; ++j) {
      const int bl = q * 4 + j;
      const int b = m0 + bl;
      float muv = aM[j] + bmv[r];
      float lsv = aS[j] + bsv[r];
      float sq  = __expf(lsv);
      float zv  = muv + sqrtf(sq) * epv[r][j];
      zout[(size_t)b * ND + d] = zv;
      AcT[bl][d]       = f2bf(zv * zv);
      AcT[bl][256 + d] = f2bf(zv);
      AqT[bl][d]       = f2bf(sq + muv * muv);
      AqT[bl][256 + d] = f2bf(muv);
    }
  }

  // ---- HOIST: phase-2 Bcsw frag loads before the barrier
  short8 b0v[2], b1v[2];
  #pragma unroll
  for (int ks = 0; ks < 2; ++ks) {
    const int kb = w * 2 + ks;              // 32-col block index (0..15)
    b0v[ks] = *reinterpret_cast<const short8*>(bcsw + (size_t)kb * 512 + lane * 8);
    b1v[ks] = *reinterpret_cast<const short8*>(bcsw + (size_t)(16 + kb) * 512 + lane * 8);
  }
  __syncthreads();   // AcT/AqT ready; Axb dead -> sW region usable

  // ---- phase 2: cluster GEMMs (64-feature slice per wave)
  f32x4 cL[2], cQ[2];
  cL[0] = cL[1] = cQ[0] = cQ[1] = (f32x4){0.f, 0.f, 0.f, 0.f};
  {
    short8 acv[2], aqv[2];
    #pragma unroll
    for (int ks = 0; ks < 2; ++ks) {
      const int kc = (w * 2 + ks) * 32 + q * 8;
      acv[ks] = *reinterpret_cast<const short8*>(&AcT[lrow][kc]);
      aqv[ks] = *reinterpret_cast<const short8*>(&AqT[lrow][kc]);
    }
    #pragma unroll
    for (int ks = 0; ks < 2; ++ks) {
      cL[0] = mfma_bf16(acv[ks], b0v[ks], cL[0]);
      cL[1] = mfma_bf16(acv[ks], b1v[ks], cL[1]);
      cQ[0] = mfma_bf16(aqv[ks], b0v[ks], cQ[0]);
      cQ[1] = mfma_bf16(aqv[ks], b1v[ks], cQ[1]);
    }
  }
  #pragma unroll
  for (int nfk = 0; nfk < 2; ++nfk)
    #pragma unroll
    for (int j = 0; j < 4; ++j) {
      sW[w][0][q * 4 + j][nfk * 16 + lrow] = cL[nfk][j];
      sW[w][1][q * 4 + j][nfk * 16 + lrow] = cQ[nfk][j];
    }
  __syncthreads();

  // ---- epilogue 2: softmax + loss partials (first 4 waves)
  if (tid < 256) {
    const int b = tid >> 4, kk = tid & 15;
    float L0 = 0.f, L1 = 0.f, Q0 = 0.f, Q1 = 0.f;
    #pragma unroll
    for (int ww = 0; ww < 8; ++ww) {
      L0 += sW[ww][0][b][kk];      L1 += sW[ww][0][b][kk + 16];
      Q0 += sW[ww][1][b][kk];      Q1 += sW[ww][1][b][kk + 16];
    }
    float l0 = -(L0 + c3k[kk]);
    float l1 = -(L1 + c3k[kk + 16]);
    float mx = fmaxf(l0, l1);
    #pragma unroll
    for (int s = 8; s; s >>= 1) mx = fmaxf(mx, __shfl_xor(mx, s));
    float p0 = __expf(l0 - mx), p1 = __expf(l1 - mx);
    float ps = p0 + p1;
    #pragma unroll
    for (int s = 8; s; s >>= 1) ps += __shfl_xor(ps, s);
    float pi0 = p0 / ps + 1e-10f;
    float pi1 = p1 / ps + 1e-10f;
    float g = pi0 * (Q0 + ckk[kk]) + pi1 * (Q1 + ckk[kk + 16]);
    #pragma unroll
    for (int s = 8; s; s >>= 1) g += __shfl_xor(g, s);
    atomicAdd(&piP[kk], pi0);
    atomicAdd(&piP[kk + 16], pi1);
    if (kk == 0) atomicAdd(&gSum, g);
  }
  __syncthreads();
  if (tid < NK)  part[(size_t)tid * 512 + blockIdx.x] = piP[tid];
  if (tid == NK) part[(size_t)NK * 512 + blockIdx.x] = 0.5f * gSum;
}

// ---- kernel 2: final reduce — parallelized ---------------------------------
__global__ __launch_bounds__(320) void final_k(const float* __restrict__ part,
                                               float* __restrict__ out) {
  __shared__ float red[33][8];
  const int tid = threadIdx.x;
  if (tid < 264) {
    const int c = tid >> 3, sg = tid & 7;
    const float4* p4 = reinterpret_cast<const float4*>(part + (size_t)c * 512 + sg * 64);
    float s = 0.f;
    #pragma unroll
    for (int i = 0; i < 16; ++i) {
      float4 v = p4[i];
      s += v.x + v.y + v.z + v.w;
    }
    red[c][sg] = s;
  }
  __syncthreads();
  if (tid >= 64) return;
  float s = 0.f;
  if (tid < 33) {
    #pragma unroll
    for (int sg = 0; sg < 8; ++sg) s += red[tid][sg];
  }
  if (tid == 32) out[NB * ND] = s;                 // batch_gaussian_loss
  float t = 0.f;
  if (tid < 32) { float mk = s / (float)NB; t = mk * __logf(mk); }
  #pragma unroll
  for (int sh = 16; sh; sh >>= 1) t += __shfl_xor(t, sh);
  if (tid == 0) out[NB * ND + 1] = t / (float)NK;  // batch_uniform_loss
}

extern "C" void kernel_launch(void* const* d_in, const int* in_sizes, int n_in,
                              void* d_out, int out_size, void* d_ws, size_t ws_size,
                              hipStream_t stream) {
  const float* x    = (const float*)d_in[0];
  const float* eps  = (const float*)d_in[1];
  const float* wmu  = (const float*)d_in[2];
  const float* bmu  = (const float*)d_in[3];
  const float* wsig = (const float*)d_in[4];
  const float* bsig = (const float*)d_in[5];
  const float* mu_c = (const float*)d_in[6];
  const float* lsc  = (const float*)d_in[7];
  float* out = (float*)d_out;

  char* ws = (char*)d_ws;
  __hip_bfloat16* wsw  = (__hip_bfloat16*)ws;                      // 256 KiB
  __hip_bfloat16* bcsw = (__hip_bfloat16*)(ws + (256u << 10));     // 32 KiB
  float* c3k  = (float*)(ws + (288u << 10));                       // 128 B
  float* ckk  = (float*)(ws + (288u << 10) + 256u);                // 128 B
  float* part = (float*)(ws + (288u << 10) + 512u);                // 66 KiB

  prep_k<<<96, 256, 0, stream>>>(wmu, wsig, wsw, mu_c, lsc, bcsw, c3k, ckk);
  mega_k<<<512, 512, 0, stream>>>(x, wsw, bmu, bsig, eps, bcsw, c3k, ckk, out, part);
  final_k<<<1, 320, 0, stream>>>(part, out);
}

// Round 21
// 24.341 us; speedup vs baseline: 1.0329x; 1.0130x over previous
//
#include <hip/hip_runtime.h>
#include <hip/hip_bf16.h>

typedef __attribute__((ext_vector_type(4))) float f32x4;
typedef __attribute__((ext_vector_type(8))) short short8;

#define NB 8192
#define ND 256
#define NK 32
#define PADF 520  // AcT/AqT row stride (ushort): 1040B; bank stride 4 -> 2-way (free)

static __device__ __forceinline__ unsigned short f2bf(float f) {
  return __builtin_bit_cast(unsigned short, __float2bfloat16(f));
}

static __device__ __forceinline__ f32x4 mfma_bf16(short8 a, short8 b, f32x4 c) {
  return __builtin_amdgcn_mfma_f32_16x16x32_bf16(a, b, c, 0, 0, 0);
}

static __device__ __forceinline__ short8 pack_bf16x8(float4 lo, float4 hi) {
  short8 r;
  r[0] = (short)f2bf(lo.x); r[1] = (short)f2bf(lo.y);
  r[2] = (short)f2bf(lo.z); r[3] = (short)f2bf(lo.w);
  r[4] = (short)f2bf(hi.x); r[5] = (short)f2bf(hi.y);
  r[6] = (short)f2bf(hi.z); r[7] = (short)f2bf(hi.w);
  return r;
}

// ---- kernel 0: prep, vectorized 8x ------------------------------------------
__global__ __launch_bounds__(256) void prep_k(const float* __restrict__ wmu,
                                              const float* __restrict__ wsig,
                                              __hip_bfloat16* __restrict__ wsw,
                                              const float* __restrict__ mu_c,
                                              const float* __restrict__ lsc,
                                              __hip_bfloat16* __restrict__ bcsw,
                                              float* __restrict__ c3k,
                                              float* __restrict__ ckk) {
  __shared__ float red1[4], red2[4];
  const int blk = blockIdx.x, tid = threadIdx.x;
  if (blk < 64) {
    int i0 = blk * 2048 + tid * 8;     // 64*2048 = 131072 = 512*256
    int f = i0 >> 9, r = i0 & 511;
    int l = r >> 3;                    // e = 0..7 within this thread
    int n = (f >> 3) * 16 + (l & 15);             // Wcat row
    int k0 = (f & 7) * 32 + ((l >> 4) << 3);      // Wcat col base
    const float* src = (n < 256) ? (wmu + n * ND + k0) : (wsig + (n - 256) * ND + k0);
    float4 v0 = *reinterpret_cast<const float4*>(src);
    float4 v1 = *reinterpret_cast<const float4*>(src + 4);
    *reinterpret_cast<short8*>(wsw + i0) = pack_bf16x8(v0, v1);
  } else {
    int k = blk - 64;     // cluster index
    int d = tid;
    float l = lsc[k * ND + d];
    float inv = __expf(-l);
    float mc = mu_c[k * ND + d];
    const int rb = k >> 4, lrow = k & 15;
    {
      int c = d;
      int kb = c >> 5, q = (c >> 3) & 3, e = c & 7;
      bcsw[(size_t)(rb * 16 + kb) * 512 + (q * 16 + lrow) * 8 + e] = __float2bfloat16(inv);
    }
    {
      int c = 256 + d;
      int kb = c >> 5, q = (c >> 3) & 3, e = c & 7;
      bcsw[(size_t)(rb * 16 + kb) * 512 + (q * 16 + lrow) * 8 + e] = __float2bfloat16(-2.f * mc * inv);
    }
    float s1 = l, s2 = mc * mc * inv;
    #pragma unroll
    for (int sh = 32; sh; sh >>= 1) { s1 += __shfl_xor(s1, sh); s2 += __shfl_xor(s2, sh); }
    int lane = tid & 63, wv = tid >> 6;
    if (lane == 0) { red1[wv] = s1; red2[wv] = s2; }
    __syncthreads();
    if (tid == 0) {
      float t1 = red1[0] + red1[1] + red1[2] + red1[3];
      float t2 = red2[0] + red2[1] + red2[2] + red2[3];
      c3k[k] = t2;
      ckk[k] = t1 + t2;
    }
  }
}

// ---- kernel 1: mega — R18 champion + eps staged via LDS (shared barrier) ---
// 512 blocks x 512 thr (8 waves, 2 blocks/CU; wall time = block critical path).
// Pipelining: round-0 mu W-frags (bM0) pre-barrier; Bcsw frags pre-barrier #2.
// NEW vs R18: eps staged COALESCED into epsb (LDS) alongside x (same barrier,
// zero new syncs); gather instrs 8 -> 2 per thread; epv read as LDS b32 after
// #1. epsb dead before #2 where sW aliases (same proof as Axb).
__global__ __launch_bounds__(512, 4) void mega_k(const float* __restrict__ xf,
                                                 const __hip_bfloat16* __restrict__ wsw,
                                                 const float* __restrict__ bmu,
                                                 const float* __restrict__ bsigv,
                                                 const float* __restrict__ eps,
                                                 const __hip_bfloat16* __restrict__ bcsw,
                                                 const float* __restrict__ c3k,
                                                 const float* __restrict__ ckk,
                                                 float* __restrict__ zout,
                                                 float* __restrict__ part) {
  __shared__ __align__(16) unsigned short AcT[16][PADF];
  __shared__ __align__(16) unsigned short AqT[16][PADF];
  __shared__ __align__(16) char uniBuf[33792];   // [Axb 8448B | epsb 16896B] -> sW after #2
  __shared__ float piP[NK];
  __shared__ float gSum;
  unsigned short (*Axb)[264] = (unsigned short (*)[264])uniBuf;
  float (*epsb)[264] = (float (*)[264])(uniBuf + 8448);
  float (*sW)[2][16][33] = (float (*)[2][16][33])uniBuf;

  const int tid = threadIdx.x, lane = tid & 63, w = tid >> 6;   // w in [0,8)
  const int lrow = lane & 15, q = lane >> 4;
  const int m0 = blockIdx.x * 16;

  if (tid < NK) piP[tid] = 0.f;
  if (tid == NK) gSum = 0.f;

  // ---- HOIST: round-0 mu W-frag loads (independent of LDS barrier)
  short8 bM0[8];
  {
    const __hip_bfloat16* pM0 = wsw + (size_t)(w * 8) * 512 + lane * 8;
    #pragma unroll
    for (int kk = 0; kk < 8; ++kk)
      bM0[kk] = *reinterpret_cast<const short8*>(pM0 + kk * 512);
  }

  // ---- prefetch bias for this wave's two rounds (rb = r*8 + w)
  float bmv[2], bsv[2];
  #pragma unroll
  for (int r = 0; r < 2; ++r) {
    const int d = (r * 8 + w) * 16 + lrow;
    bmv[r] = bmu[d];
    bsv[r] = bsigv[d];
  }

  // ---- stage x -> bf16 Axb AND eps -> epsb, both fully coalesced ----
  {
    const int r = tid >> 5, c0 = (tid & 31) * 8;
    const float* xr = xf + (size_t)(m0 + r) * ND + c0;
    float4 a0 = *reinterpret_cast<const float4*>(xr);
    float4 a1 = *reinterpret_cast<const float4*>(xr + 4);
    *reinterpret_cast<short8*>(&Axb[r][c0]) = pack_bf16x8(a0, a1);
    const float* er = eps + (size_t)(m0 + r) * ND + c0;
    float4 e0 = *reinterpret_cast<const float4*>(er);
    float4 e1 = *reinterpret_cast<const float4*>(er + 4);
    *reinterpret_cast<float4*>(&epsb[r][c0])     = e0;
    *reinterpret_cast<float4*>(&epsb[r][c0 + 4]) = e1;
  }
  __syncthreads();   // #1

  // ---- hoisted A fragments + eps values (from LDS)
  short8 aF[8];
  #pragma unroll
  for (int kk = 0; kk < 8; ++kk)
    aF[kk] = *reinterpret_cast<const short8*>(&Axb[lrow][kk * 32 + q * 8]);
  float epv[2][4];
  #pragma unroll
  for (int r = 0; r < 2; ++r) {
    const int d = (r * 8 + w) * 16 + lrow;
    #pragma unroll
    for (int j = 0; j < 4; ++j) epv[r][j] = epsb[q * 4 + j][d];
  }

  // ---- phase 1: 2 rounds of (frag loads + 16 MFMAs + epilogue)
  #pragma unroll
  for (int r = 0; r < 2; ++r) {
    const int rb = r * 8 + w;                 // mu row-block; sig = 16 + rb
    const __hip_bfloat16* pM = wsw + (size_t)(rb * 8) * 512 + lane * 8;
    const __hip_bfloat16* pS = wsw + (size_t)((16 + rb) * 8) * 512 + lane * 8;
    f32x4 aM = (f32x4){0.f, 0.f, 0.f, 0.f};
    f32x4 aS = (f32x4){0.f, 0.f, 0.f, 0.f};
    {
      short8 bM[8];
      #pragma unroll
      for (int kk = 0; kk < 8; ++kk)
        bM[kk] = (r == 0) ? bM0[kk]
                          : *reinterpret_cast<const short8*>(pM + kk * 512);
      #pragma unroll
      for (int kk = 0; kk < 8; ++kk)
        aM = mfma_bf16(aF[kk], bM[kk], aM);
    }
    {
      short8 bS[8];
      #pragma unroll
      for (int kk = 0; kk < 8; ++kk)
        bS[kk] = *reinterpret_cast<const short8*>(pS + kk * 512);
      #pragma unroll
      for (int kk = 0; kk < 8; ++kk)
        aS = mfma_bf16(aF[kk], bS[kk], aS);
    }
    // per-round epilogue: C/D layout col(lrow)->d, row(q*4+j)->b
    const int d = rb * 16 + lrow;
    #pragma unroll
    for (int j = 0; j < 4; ++j) {
      const int bl = q * 4 + j;
      const int b = m0 + bl;
      float muv = aM[j] + bmv[r];
      float lsv = aS[j] + bsv[r];
      float sq  = __expf(lsv);
      float zv  = muv + sqrtf(sq) * epv[r][j];
      zout[(size_t)b * ND + d] = zv;
      AcT[bl][d]       = f2bf(zv * zv);
      AcT[bl][256 + d] = f2bf(zv);
      AqT[bl][d]       = f2bf(sq + muv * muv);
      AqT[bl][256 + d] = f2bf(muv);
    }
  }

  // ---- HOIST: phase-2 Bcsw frag loads before the barrier
  short8 b0v[2], b1v[2];
  #pragma unroll
  for (int ks = 0; ks < 2; ++ks) {
    const int kb = w * 2 + ks;              // 32-col block index (0..15)
    b0v[ks] = *reinterpret_cast<const short8*>(bcsw + (size_t)kb * 512 + lane * 8);
    b1v[ks] = *reinterpret_cast<const short8*>(bcsw + (size_t)(16 + kb) * 512 + lane * 8);
  }
  __syncthreads();   // #2: AcT/AqT ready; Axb/epsb dead -> sW region usable

  // ---- phase 2: cluster GEMMs (64-feature slice per wave)
  f32x4 cL[2], cQ[2];
  cL[0] = cL[1] = cQ[0] = cQ[1] = (f32x4){0.f, 0.f, 0.f, 0.f};
  {
    short8 acv[2], aqv[2];
    #pragma unroll
    for (int ks = 0; ks < 2; ++ks) {
      const int kc = (w * 2 + ks) * 32 + q * 8;
      acv[ks] = *reinterpret_cast<const short8*>(&AcT[lrow][kc]);
      aqv[ks] = *reinterpret_cast<const short8*>(&AqT[lrow][kc]);
    }
    #pragma unroll
    for (int ks = 0; ks < 2; ++ks) {
      cL[0] = mfma_bf16(acv[ks], b0v[ks], cL[0]);
      cL[1] = mfma_bf16(acv[ks], b1v[ks], cL[1]);
      cQ[0] = mfma_bf16(aqv[ks], b0v[ks], cQ[0]);
      cQ[1] = mfma_bf16(aqv[ks], b1v[ks], cQ[1]);
    }
  }
  #pragma unroll
  for (int nfk = 0; nfk < 2; ++nfk)
    #pragma unroll
    for (int j = 0; j < 4; ++j) {
      sW[w][0][q * 4 + j][nfk * 16 + lrow] = cL[nfk][j];
      sW[w][1][q * 4 + j][nfk * 16 + lrow] = cQ[nfk][j];
    }
  __syncthreads();

  // ---- epilogue 2: softmax + loss partials (first 4 waves)
  if (tid < 256) {
    const int b = tid >> 4, kk = tid & 15;
    float L0 = 0.f, L1 = 0.f, Q0 = 0.f, Q1 = 0.f;
    #pragma unroll
    for (int ww = 0; ww < 8; ++ww) {
      L0 += sW[ww][0][b][kk];      L1 += sW[ww][0][b][kk + 16];
      Q0 += sW[ww][1][b][kk];      Q1 += sW[ww][1][b][kk + 16];
    }
    float l0 = -(L0 + c3k[kk]);
    float l1 = -(L1 + c3k[kk + 16]);
    float mx = fmaxf(l0, l1);
    #pragma unroll
    for (int s = 8; s; s >>= 1) mx = fmaxf(mx, __shfl_xor(mx, s));
    float p0 = __expf(l0 - mx), p1 = __expf(l1 - mx);
    float ps = p0 + p1;
    #pragma unroll
    for (int s = 8; s; s >>= 1) ps += __shfl_xor(ps, s);
    float pi0 = p0 / ps + 1e-10f;
    float pi1 = p1 / ps + 1e-10f;
    float g = pi0 * (Q0 + ckk[kk]) + pi1 * (Q1 + ckk[kk + 16]);
    #pragma unroll
    for (int s = 8; s; s >>= 1) g += __shfl_xor(g, s);
    atomicAdd(&piP[kk], pi0);
    atomicAdd(&piP[kk + 16], pi1);
    if (kk == 0) atomicAdd(&gSum, g);
  }
  __syncthreads();
  if (tid < NK)  part[(size_t)tid * 512 + blockIdx.x] = piP[tid];
  if (tid == NK) part[(size_t)NK * 512 + blockIdx.x] = 0.5f * gSum;
}

// ---- kernel 2: final reduce — parallelized ---------------------------------
__global__ __launch_bounds__(320) void final_k(const float* __restrict__ part,
                                               float* __restrict__ out) {
  __shared__ float red[33][8];
  const int tid = threadIdx.x;
  if (tid < 264) {
    const int c = tid >> 3, sg = tid & 7;
    const float4* p4 = reinterpret_cast<const float4*>(part + (size_t)c * 512 + sg * 64);
    float s = 0.f;
    #pragma unroll
    for (int i = 0; i < 16; ++i) {
      float4 v = p4[i];
      s += v.x + v.y + v.z + v.w;
    }
    red[c][sg] = s;
  }
  __syncthreads();
  if (tid >= 64) return;
  float s = 0.f;
  if (tid < 33) {
    #pragma unroll
    for (int sg = 0; sg < 8; ++sg) s += red[tid][sg];
  }
  if (tid == 32) out[NB * ND] = s;                 // batch_gaussian_loss
  float t = 0.f;
  if (tid < 32) { float mk = s / (float)NB; t = mk * __logf(mk); }
  #pragma unroll
  for (int sh = 16; sh; sh >>= 1) t += __shfl_xor(t, sh);
  if (tid == 0) out[NB * ND + 1] = t / (float)NK;  // batch_uniform_loss
}

extern "C" void kernel_launch(void* const* d_in, const int* in_sizes, int n_in,
                              void* d_out, int out_size, void* d_ws, size_t ws_size,
                              hipStream_t stream) {
  const float* x    = (const float*)d_in[0];
  const float* eps  = (const float*)d_in[1];
  const float* wmu  = (const float*)d_in[2];
  const float* bmu  = (const float*)d_in[3];
  const float* wsig = (const float*)d_in[4];
  const float* bsig = (const float*)d_in[5];
  const float* mu_c = (const float*)d_in[6];
  const float* lsc  = (const float*)d_in[7];
  float* out = (float*)d_out;

  char* ws = (char*)d_ws;
  __hip_bfloat16* wsw  = (__hip_bfloat16*)ws;                      // 256 KiB
  __hip_bfloat16* bcsw = (__hip_bfloat16*)(ws + (256u << 10));     // 32 KiB
  float* c3k  = (float*)(ws + (288u << 10));                       // 128 B
  float* ckk  = (float*)(ws + (288u << 10) + 256u);                // 128 B
  float* part = (float*)(ws + (288u << 10) + 512u);                // 66 KiB

  prep_k<<<96, 256, 0, stream>>>(wmu, wsig, wsw, mu_c, lsc, bcsw, c3k, ckk);
  mega_k<<<512, 512, 0, stream>>>(x, wsw, bmu, bsig, eps, bcsw, c3k, ckk, out, part);
  final_k<<<1, 320, 0, stream>>>(part, out);
}